// Round 16
// baseline (131.782 us; speedup 1.0000x reference)
//
#include <hip/hip_runtime.h>
#include <stdint.h>

typedef __attribute__((ext_vector_type(4))) float f32x4;
typedef __attribute__((ext_vector_type(8))) short bf16x8;
typedef __attribute__((ext_vector_type(4))) unsigned short u16x4;

#define MFMA16(a, b, c) __builtin_amdgcn_mfma_f32_16x16x32_bf16((a), (b), (c), 0, 0, 0)

static __device__ __forceinline__ unsigned short f2bf(float x) {
  union { float f; unsigned int u; } v; v.f = x;
  unsigned int r = v.u + 0x7fffu + ((v.u >> 16) & 1u);   // RNE
  return (unsigned short)(r >> 16);
}

static __device__ __forceinline__ void gload_lds16(const void* g, void* l) {
  __builtin_amdgcn_global_load_lds(
      (__attribute__((address_space(1))) void*)(g),
      (__attribute__((address_space(3))) void*)(l), 16, 0, 0);
}

// DPP lane-permute on the VALU pipe
template <int CTRL>
static __device__ __forceinline__ float dpp_mov(float x) {
  union { float f; int i; } u, r;
  u.f = x;
  r.i = __builtin_amdgcn_update_dpp(u.i, u.i, CTRL, 0xF, 0xF, false);
  return r.f;
}
static __device__ __forceinline__ float dpp_max16(float x) {
  x = fmaxf(x, dpp_mov<0xB1>(x));    // quad_perm [1,0,3,2]
  x = fmaxf(x, dpp_mov<0x4E>(x));    // quad_perm [2,3,0,1]
  x = fmaxf(x, dpp_mov<0x124>(x));   // row_ror:4
  x = fmaxf(x, dpp_mov<0x128>(x));   // row_ror:8
  return x;
}
static __device__ __forceinline__ float dpp_sum16(float x) {
  x += dpp_mov<0xB1>(x);
  x += dpp_mov<0x4E>(x);
  x += dpp_mov<0x124>(x);
  x += dpp_mov<0x128>(x);
  return x;
}

// ---------------- diagnostic fill (ws sentinel) ----------------
__global__ void fill_kernel(float* p, int n, float v) {
  int i = blockIdx.x * blockDim.x + threadIdx.x;
  if (i < n) p[i] = v;
}

// ---------------- f32 -> bf16 convert, 3 tensors, length-skipped ----------------
__global__ __launch_bounds__(256) void conv3_kernel(
    const float* __restrict__ S0, const float* __restrict__ S1, const float* __restrict__ S2,
    unsigned short* __restrict__ D0, unsigned short* __restrict__ D1,
    unsigned short* __restrict__ D2,
    const int* __restrict__ Qlen, const int* __restrict__ Vlen)
{
  const int y = blockIdx.y;
  {
    const int m0 = blockIdx.x * 4;
    const int b = m0 >> 11, s0 = m0 & 2047;
    const int L = (y == 0) ? Qlen[b] : Vlen[b];
    if (s0 >= ((L + 63) & ~63)) return;
  }
  const float* in = (y == 0) ? S0 : (y == 1) ? S1 : S2;
  unsigned short* outp = (y == 0) ? D0 : (y == 1) ? D1 : D2;
  const size_t base = ((size_t)blockIdx.x * 256 + threadIdx.x) * 16;
  const f32x4 a0 = *(const f32x4*)&in[base];
  const f32x4 a1 = *(const f32x4*)&in[base + 4];
  const f32x4 a2 = *(const f32x4*)&in[base + 8];
  const f32x4 a3 = *(const f32x4*)&in[base + 12];
  bf16x8 p0, p1;
#pragma unroll
  for (int u = 0; u < 4; ++u) {
    p0[u]     = (short)f2bf(a0[u]);
    p0[u + 4] = (short)f2bf(a1[u]);
    p1[u]     = (short)f2bf(a2[u]);
    p1[u + 4] = (short)f2bf(a3[u]);
  }
  *(bf16x8*)&outp[base]     = p0;
  *(bf16x8*)&outp[base + 8] = p1;
}

__global__ __launch_bounds__(256) void conv_kernel(
    const float* __restrict__ in, unsigned short* __restrict__ outp)
{
  const size_t base = ((size_t)blockIdx.x * 256 + threadIdx.x) * 16;
  const f32x4 a0 = *(const f32x4*)&in[base];
  const f32x4 a1 = *(const f32x4*)&in[base + 4];
  const f32x4 a2 = *(const f32x4*)&in[base + 8];
  const f32x4 a3 = *(const f32x4*)&in[base + 12];
  bf16x8 p0, p1;
#pragma unroll
  for (int u = 0; u < 4; ++u) {
    p0[u]     = (short)f2bf(a0[u]);
    p0[u + 4] = (short)f2bf(a1[u]);
    p1[u]     = (short)f2bf(a2[u]);
    p1[u + 4] = (short)f2bf(a3[u]);
  }
  *(bf16x8*)&outp[base]     = p0;
  *(bf16x8*)&outp[base + 8] = p1;
}

// ---------------- weight convert + transpose: Wt[n][k] = bf16(W[k][n]) ----------------
__global__ __launch_bounds__(256) void wtrans_kernel(
    const float* __restrict__ W0, const float* __restrict__ W1, const float* __restrict__ W2,
    unsigned short* __restrict__ T0, unsigned short* __restrict__ T1, unsigned short* __restrict__ T2)
{
  __shared__ __align__(16) float tile[64][65];
  const float* W = (blockIdx.z == 0) ? W0 : (blockIdx.z == 1) ? W1 : W2;
  unsigned short* T = (blockIdx.z == 0) ? T0 : (blockIdx.z == 1) ? T1 : T2;
  const int t = threadIdx.x;
  const int kb = blockIdx.x * 64, nb = blockIdx.y * 64;
  const int rr = t >> 4, cc = (t & 15) * 4;
#pragma unroll
  for (int p = 0; p < 4; ++p) {
    const int r = rr + p * 16;
    const f32x4 v = *(const f32x4*)&W[(size_t)(kb + r) * 1024 + nb + cc];
#pragma unroll
    for (int j = 0; j < 4; ++j) tile[r][cc + j] = v[j];
  }
  __syncthreads();
#pragma unroll
  for (int p = 0; p < 4; ++p) {
    const int n = rr + p * 16;
    u16x4 o;
#pragma unroll
    for (int j = 0; j < 4; ++j) o[j] = f2bf(tile[cc + j][n]);
    *(u16x4*)&T[(size_t)(nb + n) * 1024 + kb + cc] = o;
  }
}

// ---------------- projection GEMM: 4-deep pipeline + CU-alias-breaking m-rotation ----
// (byte-identical to round 15 -- proj no longer the bottleneck)
__global__ __launch_bounds__(256) void proj_gemm_kernel(
    const unsigned short* __restrict__ A0, const unsigned short* __restrict__ A1,
    const unsigned short* __restrict__ A2,
    const unsigned short* __restrict__ B0, const unsigned short* __restrict__ B1,
    const unsigned short* __restrict__ B2,
    unsigned short* __restrict__ O0, unsigned short* __restrict__ O1,
    unsigned short* __restrict__ O2, int zbase,
    const int* __restrict__ Qlen, const int* __restrict__ Vlen)
{
  const int z = blockIdx.z + zbase;
  const int mm = (blockIdx.x + 8 * blockIdx.y + 24 * z) & 63;   // rotated m-tile
  const int m0 = mm * 128, n0 = blockIdx.y * 128;

  {
    const int b = m0 >> 11, s0 = m0 & 2047;
    const int L = (z == 0) ? Qlen[b] : Vlen[b];
    if (s0 >= ((L + 63) & ~63)) return;
  }

  const unsigned short* Ab = (z == 0) ? A0 : (z == 1) ? A1 : A2;
  const unsigned short* Bt = (z == 0) ? B0 : (z == 1) ? B1 : B2;
  unsigned short* outp = (z == 0) ? O0 : (z == 1) ? O1 : O2;
  const float scale = (z == 0) ? 0.125f : 1.0f;

  __shared__ __align__(16) unsigned short Alds[4][128 * 32];  // 4 x 8 KB
  __shared__ __align__(16) unsigned short Blds[4][128 * 32];  // 4 x 8 KB
  const int t = threadIdx.x;
  const int lane = t & 63, w = t >> 6;
  const int wr = w >> 1, wc = w & 1;

  f32x4 acc[4][4] = {};

  const int L0 = t, L1 = t + 256;
  const int r0 = L0 >> 2, c0 = ((L0 & 3) ^ ((r0 >> 1) & 3)) * 8;
  const int r1 = L1 >> 2, c1 = ((L1 & 3) ^ ((r1 >> 1) & 3)) * 8;

#define PROJ_STAGE(tile, buf)                                                        \
  do {                                                                               \
    const int kt_ = (tile) * 32;                                                     \
    gload_lds16(&Ab[(size_t)(m0 + r0) * 1024 + kt_ + c0], &Alds[(buf)][L0 * 8]);     \
    gload_lds16(&Bt[(size_t)(n0 + r0) * 1024 + kt_ + c0], &Blds[(buf)][L0 * 8]);     \
    gload_lds16(&Ab[(size_t)(m0 + r1) * 1024 + kt_ + c1], &Alds[(buf)][L1 * 8]);     \
    gload_lds16(&Bt[(size_t)(n0 + r1) * 1024 + kt_ + c1], &Blds[(buf)][L1 * 8]);     \
  } while (0)

  PROJ_STAGE(0, 0);
  PROJ_STAGE(1, 1);
  PROJ_STAGE(2, 2);
  asm volatile("s_waitcnt vmcnt(8)" ::: "memory");
  __builtin_amdgcn_s_barrier();
  __builtin_amdgcn_sched_barrier(0);

  for (int tt = 0; tt < 32; ++tt) {
    const int cur = tt & 3;
    if (tt + 3 < 32) PROJ_STAGE(tt + 3, (tt + 3) & 3);

    const int q = lane >> 4;
    bf16x8 af[4], bfv[4];
#pragma unroll
    for (int m = 0; m < 4; ++m) {
      const int row = wr * 64 + m * 16 + (lane & 15);
      af[m] = *(const bf16x8*)&Alds[cur][row * 32 + ((q ^ ((row >> 1) & 3)) * 8)];
    }
#pragma unroll
    for (int n = 0; n < 4; ++n) {
      const int row = wc * 64 + n * 16 + (lane & 15);
      bfv[n] = *(const bf16x8*)&Blds[cur][row * 32 + ((q ^ ((row >> 1) & 3)) * 8)];
    }
    __builtin_amdgcn_s_setprio(1);
#pragma unroll
    for (int m = 0; m < 4; ++m)
#pragma unroll
      for (int n = 0; n < 4; ++n)
        acc[m][n] = MFMA16(af[m], bfv[n], acc[m][n]);
    __builtin_amdgcn_s_setprio(0);

    if (tt < 29)       asm volatile("s_waitcnt vmcnt(8)" ::: "memory");
    else if (tt == 29) asm volatile("s_waitcnt vmcnt(4)" ::: "memory");
    else               asm volatile("s_waitcnt vmcnt(0)" ::: "memory");
    __builtin_amdgcn_s_barrier();
    __builtin_amdgcn_sched_barrier(0);
  }
#undef PROJ_STAGE

#pragma unroll
  for (int mi = 0; mi < 4; ++mi) {
#pragma unroll
    for (int ni = 0; ni < 4; ++ni) {
      const int nn = n0 + wc * 64 + ni * 16 + (lane & 15);
      const int h = nn >> 6, d = nn & 63;
      const int mbase = m0 + wr * 64 + mi * 16 + ((lane >> 4) << 2);
      const int b = mbase >> 11;
      const int s = mbase & 2047;
      if (z != 2) {
#pragma unroll
        for (int j = 0; j < 4; ++j)
          outp[((size_t)(b * 16 + h) * 2048 + (s + j)) * 64 + d] = f2bf(acc[mi][ni][j] * scale);
      } else {
        u16x4 o;
#pragma unroll
        for (int j = 0; j < 4; ++j) o[j] = f2bf(acc[mi][ni][j]);
        *(u16x4*)&outp[((size_t)(b * 16 + h) * 64 + d) * 2048 + s] = o;
      }
    }
  }
}

// ---------------- flash attention: QBLK=128 (2 q-groups/wave for ILP) ----------
// qa/ka: bf16 [BH][2048][64] (q pre-scaled by 1/8). va: bf16 [BH][64][2048].
// out: f32 [B][2048][1024]. One block = one (b,h) x 128 q-rows; 4 waves x 2 x 16 rows.
// Two independent QK->softmax->PV chains per wave interleave to hide the serial
// exp/DPP/P-roundtrip latency; K/V staging + barriers amortized over 2x output.
__global__ __launch_bounds__(256) void attn_kernel(
    const unsigned short* __restrict__ qa, const unsigned short* __restrict__ ka,
    const unsigned short* __restrict__ va, const int* __restrict__ Qlen,
    const int* __restrict__ Vlen, float* __restrict__ outp)
{
  __shared__ __align__(16) unsigned short Klds[2][64 * 64];  // [kpos][d], XOR-swizzled
  __shared__ __align__(16) unsigned short Vlds[2][64 * 64];  // [d][kpos], XOR-swizzled
  __shared__ __align__(16) unsigned short Plds[4][16 * 64];
  const int t = threadIdx.x, lane = t & 63, w = t >> 6;
  const int bh = blockIdx.y, b = bh >> 4, h = bh & 15;
  const int q0 = blockIdx.x * 128;
  const int Lq = Qlen[b], Lv = Vlen[b];
  float* outb = outp + (size_t)b * 2048 * 1024 + h * 64;

  if (q0 >= Lq) {  // entire 128-row q-slab masked: zero it
    const int r = t >> 2, c0 = (t & 3) * 16;
    const f32x4 z = {0.f, 0.f, 0.f, 0.f};
#pragma unroll
    for (int jj = 0; jj < 2; ++jj)
#pragma unroll
      for (int j = 0; j < 4; ++j)
        *(f32x4*)&outb[(size_t)(q0 + jj * 64 + r) * 1024 + c0 + j * 4] = z;
    return;
  }

  const unsigned short* qb = qa + (size_t)bh * 2048 * 64;
  const unsigned short* kb = ka + (size_t)bh * 2048 * 64;
  const unsigned short* vb = va + (size_t)bh * 64 * 2048;

  const int sr0 = t >> 3, sc0 = t & 7;
  const int sr1 = (t + 256) >> 3, sc1 = (t + 256) & 7;
  const int sd0 = sr0 * 64 + ((sc0 ^ (sr0 & 7)) * 8);
  const int sd1 = sr1 * 64 + ((sc1 ^ (sr1 & 7)) * 8);

  // Q fragments for both q-groups (g*64 row offset)
  bf16x8 aq[2][2];
#pragma unroll
  for (int g = 0; g < 2; ++g) {
    const int qrow = q0 + g * 64 + w * 16 + (lane & 15);
#pragma unroll
    for (int f = 0; f < 2; ++f)
      aq[g][f] = *(const bf16x8*)&qb[(size_t)qrow * 64 + (lane >> 4) * 8 + f * 32];
  }

  float m_run[2][4], l_run[2][4];
  f32x4 acc_o[2][4] = {};
#pragma unroll
  for (int g = 0; g < 2; ++g)
#pragma unroll
    for (int j = 0; j < 4; ++j) { m_run[g][j] = -3.0e38f; l_run[g][j] = 0.0f; }

  const int nt = (Lv + 63) >> 6;

  bf16x8 kr0 = *(const bf16x8*)&kb[(size_t)sr0 * 64 + sc0 * 8];
  bf16x8 kr1 = *(const bf16x8*)&kb[(size_t)sr1 * 64 + sc1 * 8];
  bf16x8 vr0 = *(const bf16x8*)&vb[(size_t)sr0 * 2048 + sc0 * 8];
  bf16x8 vr1 = *(const bf16x8*)&vb[(size_t)sr1 * 2048 + sc1 * 8];
  *(bf16x8*)&Klds[0][sd0] = kr0;  *(bf16x8*)&Klds[0][sd1] = kr1;
  *(bf16x8*)&Vlds[0][sd0] = vr0;  *(bf16x8*)&Vlds[0][sd1] = vr1;

  for (int kt = 0; kt < nt; ++kt) {
    __syncthreads();
    const int cur = kt & 1;
    const unsigned short* Kc = &Klds[cur][0];
    const unsigned short* Vc = &Vlds[cur][0];
    const int k0 = kt * 64;

    const bool more = (kt + 1) < nt;
    if (more) {
      const int kn = k0 + 64;
      kr0 = *(const bf16x8*)&kb[(size_t)(kn + sr0) * 64 + sc0 * 8];
      kr1 = *(const bf16x8*)&kb[(size_t)(kn + sr1) * 64 + sc1 * 8];
      vr0 = *(const bf16x8*)&vb[(size_t)sr0 * 2048 + kn + sc0 * 8];
      vr1 = *(const bf16x8*)&vb[(size_t)sr1 * 2048 + kn + sc1 * 8];
    }

    // two independent q-group chains; unrolled so the scheduler interleaves them
#pragma unroll
    for (int g = 0; g < 2; ++g) {
      // QK^T
      f32x4 s4[4];
      __builtin_amdgcn_s_setprio(1);
#pragma unroll
      for (int kbk = 0; kbk < 4; ++kbk) {
        const int row = kbk * 16 + (lane & 15);
        f32x4 acc = {0.f, 0.f, 0.f, 0.f};
#pragma unroll
        for (int ds = 0; ds < 2; ++ds) {
          const int col = (((lane >> 4) * 8) + ds * 32) ^ ((row & 7) << 3);
          const bf16x8 bk = *(const bf16x8*)&Kc[row * 64 + col];
          acc = MFMA16(aq[g][ds], bk, acc);
        }
        if (k0 + row >= Lv) {
#pragma unroll
          for (int j = 0; j < 4; ++j) acc[j] = -1e30f;
        }
        s4[kbk] = acc;
      }
      __builtin_amdgcn_s_setprio(0);

      // online softmax: rowmax via DPP
      float mn[4], esc[4];
#pragma unroll
      for (int j = 0; j < 4; ++j) {
        float rm = fmaxf(fmaxf(s4[0][j], s4[1][j]), fmaxf(s4[2][j], s4[3][j]));
        rm = dpp_max16(rm);
        mn[j] = fmaxf(m_run[g][j], rm);
        esc[j] = __expf(m_run[g][j] - mn[j]);
        m_run[g][j] = mn[j];
      }

      float p[4][4];
      float rs[4] = {0.f, 0.f, 0.f, 0.f};
#pragma unroll
      for (int kbk = 0; kbk < 4; ++kbk)
#pragma unroll
        for (int j = 0; j < 4; ++j) {
          p[kbk][j] = __expf(s4[kbk][j] - mn[j]);
          rs[j] += p[kbk][j];
        }

      // P -> per-wave LDS (reused across g; wave-internal lgkm ordering suffices)
      unsigned short* pl = &Plds[w][0];
#pragma unroll
      for (int kbk = 0; kbk < 4; ++kbk)
#pragma unroll
        for (int j = 0; j < 4; ++j) {
          const int row = (lane >> 4) * 4 + j;
          const int col = (kbk * 16 + (lane & 15)) ^ ((row & 7) << 3);
          pl[row * 64 + col] = f2bf(p[kbk][j]);
        }

#pragma unroll
      for (int j = 0; j < 4; ++j) {
        const float s = dpp_sum16(rs[j]);
        l_run[g][j] = l_run[g][j] * esc[j] + s;
      }
#pragma unroll
      for (int d = 0; d < 4; ++d)
#pragma unroll
        for (int j = 0; j < 4; ++j) acc_o[g][d][j] *= esc[j];

      bf16x8 pf[2];
#pragma unroll
      for (int ks = 0; ks < 2; ++ks) {
        const int row = lane & 15;
        const int col = ((lane >> 4) * 8 + ks * 32) ^ ((row & 7) << 3);
        pf[ks] = *(const bf16x8*)&pl[row * 64 + col];
      }

      // PV
      __builtin_amdgcn_s_setprio(1);
#pragma unroll
      for (int db = 0; db < 4; ++db) {
#pragma unroll
        for (int ks = 0; ks < 2; ++ks) {
          const int vrow = db * 16 + (lane & 15);
          const int vcol = ((lane >> 4) * 8 + ks * 32) ^ ((vrow & 7) << 3);
          const bf16x8 vf = *(const bf16x8*)&Vc[vrow * 64 + vcol];
          acc_o[g][db] = MFMA16(pf[ks], vf, acc_o[g][db]);
        }
      }
      __builtin_amdgcn_s_setprio(0);
    }

    if (more) {
      unsigned short* Kn = &Klds[cur ^ 1][0];
      unsigned short* Vn = &Vlds[cur ^ 1][0];
      *(bf16x8*)&Kn[sd0] = kr0;  *(bf16x8*)&Kn[sd1] = kr1;
      *(bf16x8*)&Vn[sd0] = vr0;  *(bf16x8*)&Vn[sd1] = vr1;
    }
  }

  // epilogue: normalize, Q_len mask, write f32
#pragma unroll
  for (int g = 0; g < 2; ++g)
#pragma unroll
    for (int j = 0; j < 4; ++j) {
      const int row = q0 + g * 64 + w * 16 + (lane >> 4) * 4 + j;
      const float rl = 1.0f / l_run[g][j];
#pragma unroll
      for (int db = 0; db < 4; ++db) {
        const float v = acc_o[g][db][j] * rl;
        outb[(size_t)row * 1024 + db * 16 + (lane & 15)] = (row < Lq) ? v : 0.0f;
      }
    }
}

extern "C" void kernel_launch(void* const* d_in, const int* in_sizes, int n_in,
                              void* d_out, int out_size, void* d_ws, size_t ws_size,
                              hipStream_t stream) {
  float* out = (float*)d_out;

  const float* Qs = (const float*)d_in[0];
  const float* Ks = (const float*)d_in[1];
  const float* Vs = (const float*)d_in[2];
  const float* WQ = (const float*)d_in[3];
  const float* WK = (const float*)d_in[4];
  const float* WV = (const float*)d_in[5];
  const int* Qlen = (const int*)d_in[6];
  const int* Vlen = (const int*)d_in[7];

  unsigned short* WQt = (unsigned short*)d_ws;
  unsigned short* WKt = WQt + (size_t)1024 * 1024;
  unsigned short* WVt = WKt + (size_t)1024 * 1024;
  unsigned short* qa  = WVt + (size_t)1024 * 1024;
  unsigned short* ka  = qa + (size_t)8192 * 1024;
  unsigned short* va  = ka + (size_t)8192 * 1024;
  unsigned short* ext = va + (size_t)8192 * 1024;   // optional 3rd A-buffer

  // converted-A buffers: d_out used as scratch (attn rewrites it fully at the end)
  unsigned short* cA = (unsigned short*)d_out;              // 8M bf16 = 16 MB
  unsigned short* cB = cA + (size_t)8192 * 1024;            // second 16 MB

  const size_t base_need = ((size_t)3 * 1024 * 1024 + (size_t)3 * 8192 * 1024) * 2;
  const size_t ext_need  = base_need + (size_t)8192 * 1024 * 2;

  if (ws_size < base_need) {
    fill_kernel<<<(out_size + 255) / 256, 256, 0, stream>>>(out, out_size, 256.0f);
    return;
  }

  wtrans_kernel<<<dim3(16, 16, 3), 256, 0, stream>>>(WQ, WK, WV, WQt, WKt, WVt);

  if (ws_size >= ext_need) {
    conv3_kernel<<<dim3(2048, 3), 256, 0, stream>>>(Qs, Ks, Vs, cA, cB, ext, Qlen, Vlen);
    proj_gemm_kernel<<<dim3(64, 8, 3), 256, 0, stream>>>(
        cA, cB, ext, WQt, WKt, WVt, qa, ka, va, 0, Qlen, Vlen);
  } else {
    conv_kernel<<<2048, 256, 0, stream>>>(Qs, cA);
    conv_kernel<<<2048, 256, 0, stream>>>(Ks, cB);
    proj_gemm_kernel<<<dim3(64, 8, 2), 256, 0, stream>>>(
        cA, cB, cB, WQt, WKt, WVt, qa, ka, va, 0, Qlen, Vlen);
    conv_kernel<<<2048, 256, 0, stream>>>(Vs, cA);
    proj_gemm_kernel<<<dim3(64, 8, 1), 256, 0, stream>>>(
        cA, cA, cA, WQt, WKt, WVt, qa, ka, va, 2, Qlen, Vlen);
  }
  attn_kernel<<<dim3(16, 64), 256, 0, stream>>>(qa, ka, va, Qlen, Vlen, out);
}

// Round 17
// 120.312 us; speedup vs baseline: 1.0953x; 1.0953x over previous
//
#include <hip/hip_runtime.h>
#include <stdint.h>

typedef __attribute__((ext_vector_type(4))) float f32x4;
typedef __attribute__((ext_vector_type(8))) short bf16x8;
typedef __attribute__((ext_vector_type(4))) unsigned short u16x4;

#define MFMA16(a, b, c) __builtin_amdgcn_mfma_f32_16x16x32_bf16((a), (b), (c), 0, 0, 0)

static __device__ __forceinline__ unsigned short f2bf(float x) {
  union { float f; unsigned int u; } v; v.f = x;
  unsigned int r = v.u + 0x7fffu + ((v.u >> 16) & 1u);   // RNE
  return (unsigned short)(r >> 16);
}

static __device__ __forceinline__ void gload_lds16(const void* g, void* l) {
  __builtin_amdgcn_global_load_lds(
      (__attribute__((address_space(1))) void*)(g),
      (__attribute__((address_space(3))) void*)(l), 16, 0, 0);
}

// DPP lane-permute on the VALU pipe
template <int CTRL>
static __device__ __forceinline__ float dpp_mov(float x) {
  union { float f; int i; } u, r;
  u.f = x;
  r.i = __builtin_amdgcn_update_dpp(u.i, u.i, CTRL, 0xF, 0xF, false);
  return r.f;
}
static __device__ __forceinline__ float dpp_max16(float x) {
  x = fmaxf(x, dpp_mov<0xB1>(x));    // quad_perm [1,0,3,2]
  x = fmaxf(x, dpp_mov<0x4E>(x));    // quad_perm [2,3,0,1]
  x = fmaxf(x, dpp_mov<0x124>(x));   // row_ror:4
  x = fmaxf(x, dpp_mov<0x128>(x));   // row_ror:8
  return x;
}
static __device__ __forceinline__ float dpp_sum16(float x) {
  x += dpp_mov<0xB1>(x);
  x += dpp_mov<0x4E>(x);
  x += dpp_mov<0x124>(x);
  x += dpp_mov<0x128>(x);
  return x;
}

// ---------------- diagnostic fill (ws sentinel) ----------------
__global__ void fill_kernel(float* p, int n, float v) {
  int i = blockIdx.x * blockDim.x + threadIdx.x;
  if (i < n) p[i] = v;
}

// ---------------- f32 -> bf16 convert, 3 tensors, length-skipped ----------------
__global__ __launch_bounds__(256) void conv3_kernel(
    const float* __restrict__ S0, const float* __restrict__ S1, const float* __restrict__ S2,
    unsigned short* __restrict__ D0, unsigned short* __restrict__ D1,
    unsigned short* __restrict__ D2,
    const int* __restrict__ Qlen, const int* __restrict__ Vlen)
{
  const int y = blockIdx.y;
  {
    const int m0 = blockIdx.x * 4;
    const int b = m0 >> 11, s0 = m0 & 2047;
    const int L = (y == 0) ? Qlen[b] : Vlen[b];
    if (s0 >= ((L + 63) & ~63)) return;
  }
  const float* in = (y == 0) ? S0 : (y == 1) ? S1 : S2;
  unsigned short* outp = (y == 0) ? D0 : (y == 1) ? D1 : D2;
  const size_t base = ((size_t)blockIdx.x * 256 + threadIdx.x) * 16;
  const f32x4 a0 = *(const f32x4*)&in[base];
  const f32x4 a1 = *(const f32x4*)&in[base + 4];
  const f32x4 a2 = *(const f32x4*)&in[base + 8];
  const f32x4 a3 = *(const f32x4*)&in[base + 12];
  bf16x8 p0, p1;
#pragma unroll
  for (int u = 0; u < 4; ++u) {
    p0[u]     = (short)f2bf(a0[u]);
    p0[u + 4] = (short)f2bf(a1[u]);
    p1[u]     = (short)f2bf(a2[u]);
    p1[u + 4] = (short)f2bf(a3[u]);
  }
  *(bf16x8*)&outp[base]     = p0;
  *(bf16x8*)&outp[base + 8] = p1;
}

__global__ __launch_bounds__(256) void conv_kernel(
    const float* __restrict__ in, unsigned short* __restrict__ outp)
{
  const size_t base = ((size_t)blockIdx.x * 256 + threadIdx.x) * 16;
  const f32x4 a0 = *(const f32x4*)&in[base];
  const f32x4 a1 = *(const f32x4*)&in[base + 4];
  const f32x4 a2 = *(const f32x4*)&in[base + 8];
  const f32x4 a3 = *(const f32x4*)&in[base + 12];
  bf16x8 p0, p1;
#pragma unroll
  for (int u = 0; u < 4; ++u) {
    p0[u]     = (short)f2bf(a0[u]);
    p0[u + 4] = (short)f2bf(a1[u]);
    p1[u]     = (short)f2bf(a2[u]);
    p1[u + 4] = (short)f2bf(a3[u]);
  }
  *(bf16x8*)&outp[base]     = p0;
  *(bf16x8*)&outp[base + 8] = p1;
}

// ---------------- weight convert + transpose: Wt[n][k] = bf16(W[k][n]) ----------------
__global__ __launch_bounds__(256) void wtrans_kernel(
    const float* __restrict__ W0, const float* __restrict__ W1, const float* __restrict__ W2,
    unsigned short* __restrict__ T0, unsigned short* __restrict__ T1, unsigned short* __restrict__ T2)
{
  __shared__ __align__(16) float tile[64][65];
  const float* W = (blockIdx.z == 0) ? W0 : (blockIdx.z == 1) ? W1 : W2;
  unsigned short* T = (blockIdx.z == 0) ? T0 : (blockIdx.z == 1) ? T1 : T2;
  const int t = threadIdx.x;
  const int kb = blockIdx.x * 64, nb = blockIdx.y * 64;
  const int rr = t >> 4, cc = (t & 15) * 4;
#pragma unroll
  for (int p = 0; p < 4; ++p) {
    const int r = rr + p * 16;
    const f32x4 v = *(const f32x4*)&W[(size_t)(kb + r) * 1024 + nb + cc];
#pragma unroll
    for (int j = 0; j < 4; ++j) tile[r][cc + j] = v[j];
  }
  __syncthreads();
#pragma unroll
  for (int p = 0; p < 4; ++p) {
    const int n = rr + p * 16;
    u16x4 o;
#pragma unroll
    for (int j = 0; j < 4; ++j) o[j] = f2bf(tile[cc + j][n]);
    *(u16x4*)&T[(size_t)(nb + n) * 1024 + kb + cc] = o;
  }
}

// ---------------- projection GEMM: 4-deep pipeline + CU-alias-breaking m-rotation ----
// (byte-identical to round 15)
__global__ __launch_bounds__(256) void proj_gemm_kernel(
    const unsigned short* __restrict__ A0, const unsigned short* __restrict__ A1,
    const unsigned short* __restrict__ A2,
    const unsigned short* __restrict__ B0, const unsigned short* __restrict__ B1,
    const unsigned short* __restrict__ B2,
    unsigned short* __restrict__ O0, unsigned short* __restrict__ O1,
    unsigned short* __restrict__ O2, int zbase,
    const int* __restrict__ Qlen, const int* __restrict__ Vlen)
{
  const int z = blockIdx.z + zbase;
  const int mm = (blockIdx.x + 8 * blockIdx.y + 24 * z) & 63;   // rotated m-tile
  const int m0 = mm * 128, n0 = blockIdx.y * 128;

  {
    const int b = m0 >> 11, s0 = m0 & 2047;
    const int L = (z == 0) ? Qlen[b] : Vlen[b];
    if (s0 >= ((L + 63) & ~63)) return;
  }

  const unsigned short* Ab = (z == 0) ? A0 : (z == 1) ? A1 : A2;
  const unsigned short* Bt = (z == 0) ? B0 : (z == 1) ? B1 : B2;
  unsigned short* outp = (z == 0) ? O0 : (z == 1) ? O1 : O2;
  const float scale = (z == 0) ? 0.125f : 1.0f;

  __shared__ __align__(16) unsigned short Alds[4][128 * 32];  // 4 x 8 KB
  __shared__ __align__(16) unsigned short Blds[4][128 * 32];  // 4 x 8 KB
  const int t = threadIdx.x;
  const int lane = t & 63, w = t >> 6;
  const int wr = w >> 1, wc = w & 1;

  f32x4 acc[4][4] = {};

  const int L0 = t, L1 = t + 256;
  const int r0 = L0 >> 2, c0 = ((L0 & 3) ^ ((r0 >> 1) & 3)) * 8;
  const int r1 = L1 >> 2, c1 = ((L1 & 3) ^ ((r1 >> 1) & 3)) * 8;

#define PROJ_STAGE(tile, buf)                                                        \
  do {                                                                               \
    const int kt_ = (tile) * 32;                                                     \
    gload_lds16(&Ab[(size_t)(m0 + r0) * 1024 + kt_ + c0], &Alds[(buf)][L0 * 8]);     \
    gload_lds16(&Bt[(size_t)(n0 + r0) * 1024 + kt_ + c0], &Blds[(buf)][L0 * 8]);     \
    gload_lds16(&Ab[(size_t)(m0 + r1) * 1024 + kt_ + c1], &Alds[(buf)][L1 * 8]);     \
    gload_lds16(&Bt[(size_t)(n0 + r1) * 1024 + kt_ + c1], &Blds[(buf)][L1 * 8]);     \
  } while (0)

  PROJ_STAGE(0, 0);
  PROJ_STAGE(1, 1);
  PROJ_STAGE(2, 2);
  asm volatile("s_waitcnt vmcnt(8)" ::: "memory");
  __builtin_amdgcn_s_barrier();
  __builtin_amdgcn_sched_barrier(0);

  for (int tt = 0; tt < 32; ++tt) {
    const int cur = tt & 3;
    if (tt + 3 < 32) PROJ_STAGE(tt + 3, (tt + 3) & 3);

    const int q = lane >> 4;
    bf16x8 af[4], bfv[4];
#pragma unroll
    for (int m = 0; m < 4; ++m) {
      const int row = wr * 64 + m * 16 + (lane & 15);
      af[m] = *(const bf16x8*)&Alds[cur][row * 32 + ((q ^ ((row >> 1) & 3)) * 8)];
    }
#pragma unroll
    for (int n = 0; n < 4; ++n) {
      const int row = wc * 64 + n * 16 + (lane & 15);
      bfv[n] = *(const bf16x8*)&Blds[cur][row * 32 + ((q ^ ((row >> 1) & 3)) * 8)];
    }
    __builtin_amdgcn_s_setprio(1);
#pragma unroll
    for (int m = 0; m < 4; ++m)
#pragma unroll
      for (int n = 0; n < 4; ++n)
        acc[m][n] = MFMA16(af[m], bfv[n], acc[m][n]);
    __builtin_amdgcn_s_setprio(0);

    if (tt < 29)       asm volatile("s_waitcnt vmcnt(8)" ::: "memory");
    else if (tt == 29) asm volatile("s_waitcnt vmcnt(4)" ::: "memory");
    else               asm volatile("s_waitcnt vmcnt(0)" ::: "memory");
    __builtin_amdgcn_s_barrier();
    __builtin_amdgcn_sched_barrier(0);
  }
#undef PROJ_STAGE

#pragma unroll
  for (int mi = 0; mi < 4; ++mi) {
#pragma unroll
    for (int ni = 0; ni < 4; ++ni) {
      const int nn = n0 + wc * 64 + ni * 16 + (lane & 15);
      const int h = nn >> 6, d = nn & 63;
      const int mbase = m0 + wr * 64 + mi * 16 + ((lane >> 4) << 2);
      const int b = mbase >> 11;
      const int s = mbase & 2047;
      if (z != 2) {
#pragma unroll
        for (int j = 0; j < 4; ++j)
          outp[((size_t)(b * 16 + h) * 2048 + (s + j)) * 64 + d] = f2bf(acc[mi][ni][j] * scale);
      } else {
        u16x4 o;
#pragma unroll
        for (int j = 0; j < 4; ++j) o[j] = f2bf(acc[mi][ni][j]);
        *(u16x4*)&outp[((size_t)(b * 16 + h) * 64 + d) * 2048 + s] = o;
      }
    }
  }
}

// ---------------- flash attention: barrier-free wave-private KV-split ----------
// qa/ka: bf16 [BH][2048][64] (q pre-scaled by 1/8). va: bf16 [BH][64][2048].
// One block = 16 q-rows; wave w owns KV tiles kt === w (mod 4), KVBLK=32, staged in a
// PRIVATE 9KB LDS slice (ds ordering is wave-internal -> ZERO barriers in main loop).
// Per-wave online-softmax partials merged once at the end (flash split-KV combine).
__global__ __launch_bounds__(256) void attn_kernel(
    const unsigned short* __restrict__ qa, const unsigned short* __restrict__ ka,
    const unsigned short* __restrict__ va, const int* __restrict__ Qlen,
    const int* __restrict__ Vlen, float* __restrict__ outp)
{
  __shared__ __align__(16) unsigned char smem[36864];   // 4 x 9KB wave slices / combine
  const int t = threadIdx.x, lane = t & 63, w = t >> 6;
  const int bh = blockIdx.y, b = bh >> 4, h = bh & 15;
  const int q0 = blockIdx.x * 16;
  const int Lq = Qlen[b], Lv = Vlen[b];
  float* outb = outp + (size_t)b * 2048 * 1024 + h * 64;

  if (q0 >= Lq) {  // masked q-slab: zero 16x64
    const int r = t >> 4, c0 = (t & 15) * 4;
    const f32x4 z = {0.f, 0.f, 0.f, 0.f};
    *(f32x4*)&outb[(size_t)(q0 + r) * 1024 + c0] = z;
    return;
  }

  const unsigned short* qb = qa + (size_t)bh * 2048 * 64;
  const unsigned short* kb = ka + (size_t)bh * 2048 * 64;
  const unsigned short* vb = va + (size_t)bh * 64 * 2048;

  unsigned short* Klds = (unsigned short*)(smem + w * 9216);          // [32][64] swz c^(r&7)
  unsigned short* Vlds = (unsigned short*)(smem + w * 9216 + 4096);   // [64][32] swz c^(r&3)
  unsigned short* Plds = (unsigned short*)(smem + w * 9216 + 8192);   // [16][32] swz c^(r&3)

  // Q A-fragments: q-row = lane&15, k = (lane>>4)*8 + f*32
  bf16x8 aq[2];
  {
    const int qrow = q0 + (lane & 15);
#pragma unroll
    for (int f = 0; f < 2; ++f)
      aq[f] = *(const bf16x8*)&qb[(size_t)qrow * 64 + (lane >> 4) * 8 + f * 32];
  }

  float m_run[4], l_run[4];
  f32x4 acc_o[4] = {};
#pragma unroll
  for (int j = 0; j < 4; ++j) { m_run[j] = -3.0e38f; l_run[j] = 0.0f; }

  const int nt = (Lv + 31) >> 5;   // KVBLK=32 tiles

  // staging geometry: K chunk ci=lane+64i: r=ci>>3, cs=ci&7; V: r=ci>>2, cs=ci&3
  bf16x8 krg[4], vrg[4];
  int kt = w;
  if (kt < nt) {
    const int k0 = kt * 32;
#pragma unroll
    for (int i = 0; i < 4; ++i) {
      const int ci = lane + i * 64;
      krg[i] = *(const bf16x8*)&kb[(size_t)(k0 + (ci >> 3)) * 64 + (ci & 7) * 8];
      vrg[i] = *(const bf16x8*)&vb[(size_t)(ci >> 2) * 2048 + k0 + (ci & 3) * 8];
    }
#pragma unroll
    for (int i = 0; i < 4; ++i) {
      const int ci = lane + i * 64;
      const int kr = ci >> 3, kc = ci & 7;
      const int vr = ci >> 2, vc = ci & 3;
      *(bf16x8*)&Klds[kr * 64 + ((kc ^ (kr & 7)) * 8)] = krg[i];
      *(bf16x8*)&Vlds[vr * 32 + ((vc ^ (vr & 3)) * 8)] = vrg[i];
    }
  }

  for (; kt < nt; kt += 4) {
    const int k0 = kt * 32;
    const bool more = (kt + 4) < nt;
    if (more) {
      const int kn = k0 + 128;
#pragma unroll
      for (int i = 0; i < 4; ++i) {
        const int ci = lane + i * 64;
        krg[i] = *(const bf16x8*)&kb[(size_t)(kn + (ci >> 3)) * 64 + (ci & 7) * 8];
        vrg[i] = *(const bf16x8*)&vb[(size_t)(ci >> 2) * 2048 + kn + (ci & 3) * 8];
      }
    }

    // QK^T: 2 kbk x 2 ds = 4 MFMA
    f32x4 s4[2];
    __builtin_amdgcn_s_setprio(1);
#pragma unroll
    for (int kbk = 0; kbk < 2; ++kbk) {
      const int row = kbk * 16 + (lane & 15);
      f32x4 acc = {0.f, 0.f, 0.f, 0.f};
#pragma unroll
      for (int ds = 0; ds < 2; ++ds) {
        const int col = (((lane >> 4) * 8) + ds * 32) ^ ((row & 7) << 3);
        const bf16x8 bk = *(const bf16x8*)&Klds[row * 64 + col];
        acc = MFMA16(aq[ds], bk, acc);
      }
      if (k0 + row >= Lv) {
#pragma unroll
        for (int j = 0; j < 4; ++j) acc[j] = -1e30f;
      }
      s4[kbk] = acc;
    }
    __builtin_amdgcn_s_setprio(0);

    // online softmax (DPP rowmax over 16 lanes)
    float mn[4], esc[4];
#pragma unroll
    for (int j = 0; j < 4; ++j) {
      float rm = fmaxf(s4[0][j], s4[1][j]);
      rm = dpp_max16(rm);
      mn[j] = fmaxf(m_run[j], rm);
      esc[j] = __expf(m_run[j] - mn[j]);
      m_run[j] = mn[j];
    }

    float p[2][4];
    float rs[4] = {0.f, 0.f, 0.f, 0.f};
#pragma unroll
    for (int kbk = 0; kbk < 2; ++kbk)
#pragma unroll
      for (int j = 0; j < 4; ++j) {
        p[kbk][j] = __expf(s4[kbk][j] - mn[j]);
        rs[j] += p[kbk][j];
      }

    // P -> wave-private LDS (swizzled); latency hides under DPP sum + rescale
#pragma unroll
    for (int kbk = 0; kbk < 2; ++kbk)
#pragma unroll
      for (int j = 0; j < 4; ++j) {
        const int row = (lane >> 4) * 4 + j;
        const int pcol = kbk * 16 + (lane & 15);
        Plds[row * 32 + (((pcol >> 3) ^ (row & 3)) * 8) + (pcol & 7)] = f2bf(p[kbk][j]);
      }

#pragma unroll
    for (int j = 0; j < 4; ++j) {
      const float s = dpp_sum16(rs[j]);
      l_run[j] = l_run[j] * esc[j] + s;
    }
#pragma unroll
    for (int d = 0; d < 4; ++d)
#pragma unroll
      for (int j = 0; j < 4; ++j) acc_o[d][j] *= esc[j];

    // P A-fragment: row=lane&15, k=(lane>>4)*8 -> single swizzled b128 read
    bf16x8 pf;
    {
      const int row = lane & 15;
      pf = *(const bf16x8*)&Plds[row * 32 + (((lane >> 4) ^ (row & 3)) * 8)];
    }

    // PV: 4 MFMA (K=32 exactly one fragment)
    __builtin_amdgcn_s_setprio(1);
#pragma unroll
    for (int db = 0; db < 4; ++db) {
      const int vrow = db * 16 + (lane & 15);
      const int vch = (lane >> 4) ^ (vrow & 3);
      const bf16x8 vf = *(const bf16x8*)&Vlds[vrow * 32 + vch * 8];
      acc_o[db] = MFMA16(pf, vf, acc_o[db]);
    }
    __builtin_amdgcn_s_setprio(0);

    // write prefetched tile into the (private) buffer after all reads of current
    if (more) {
#pragma unroll
      for (int i = 0; i < 4; ++i) {
        const int ci = lane + i * 64;
        const int kr = ci >> 3, kc = ci & 7;
        const int vr = ci >> 2, vc = ci & 3;
        *(bf16x8*)&Klds[kr * 64 + ((kc ^ (kr & 7)) * 8)] = krg[i];
        *(bf16x8*)&Vlds[vr * 32 + ((vc ^ (vr & 3)) * 8)] = vrg[i];
      }
    }
  }

  // ---- split-KV combine: 2 barriers, then wave 0 writes ----
  __syncthreads();
  float* comb = (float*)smem;                    // [4][64][24] = 24 KB (aliases slices)
  {
    float* my = comb + ((size_t)w * 64 + lane) * 24;
#pragma unroll
    for (int j = 0; j < 4; ++j) { my[j] = m_run[j]; my[4 + j] = l_run[j]; }
#pragma unroll
    for (int db = 0; db < 4; ++db)
#pragma unroll
      for (int j = 0; j < 4; ++j) my[8 + db * 4 + j] = acc_o[db][j];
  }
  __syncthreads();
  if (w == 0) {
#pragma unroll
    for (int ww = 1; ww < 4; ++ww) {
      const float* o = comb + ((size_t)ww * 64 + lane) * 24;
#pragma unroll
      for (int j = 0; j < 4; ++j) {
        const float mo = o[j];
        const float M = fmaxf(m_run[j], mo);
        const float e0 = __expf(m_run[j] - M);
        const float e1 = __expf(mo - M);
        l_run[j] = l_run[j] * e0 + o[4 + j] * e1;
#pragma unroll
        for (int db = 0; db < 4; ++db)
          acc_o[db][j] = acc_o[db][j] * e0 + o[8 + db * 4 + j] * e1;
        m_run[j] = M;
      }
    }
#pragma unroll
    for (int j = 0; j < 4; ++j) {
      const int row = q0 + (lane >> 4) * 4 + j;
      const float rl = 1.0f / l_run[j];
#pragma unroll
      for (int db = 0; db < 4; ++db) {
        const float v = acc_o[db][j] * rl;
        outb[(size_t)row * 1024 + db * 16 + (lane & 15)] = (row < Lq) ? v : 0.0f;
      }
    }
  }
}

extern "C" void kernel_launch(void* const* d_in, const int* in_sizes, int n_in,
                              void* d_out, int out_size, void* d_ws, size_t ws_size,
                              hipStream_t stream) {
  float* out = (float*)d_out;

  const float* Qs = (const float*)d_in[0];
  const float* Ks = (const float*)d_in[1];
  const float* Vs = (const float*)d_in[2];
  const float* WQ = (const float*)d_in[3];
  const float* WK = (const float*)d_in[4];
  const float* WV = (const float*)d_in[5];
  const int* Qlen = (const int*)d_in[6];
  const int* Vlen = (const int*)d_in[7];

  unsigned short* WQt = (unsigned short*)d_ws;
  unsigned short* WKt = WQt + (size_t)1024 * 1024;
  unsigned short* WVt = WKt + (size_t)1024 * 1024;
  unsigned short* qa  = WVt + (size_t)1024 * 1024;
  unsigned short* ka  = qa + (size_t)8192 * 1024;
  unsigned short* va  = ka + (size_t)8192 * 1024;
  unsigned short* ext = va + (size_t)8192 * 1024;   // optional 3rd A-buffer

  // converted-A buffers: d_out used as scratch (attn rewrites it fully at the end)
  unsigned short* cA = (unsigned short*)d_out;              // 8M bf16 = 16 MB
  unsigned short* cB = cA + (size_t)8192 * 1024;            // second 16 MB

  const size_t base_need = ((size_t)3 * 1024 * 1024 + (size_t)3 * 8192 * 1024) * 2;
  const size_t ext_need  = base_need + (size_t)8192 * 1024 * 2;

  if (ws_size < base_need) {
    fill_kernel<<<(out_size + 255) / 256, 256, 0, stream>>>(out, out_size, 256.0f);
    return;
  }

  wtrans_kernel<<<dim3(16, 16, 3), 256, 0, stream>>>(WQ, WK, WV, WQt, WKt, WVt);

  if (ws_size >= ext_need) {
    conv3_kernel<<<dim3(2048, 3), 256, 0, stream>>>(Qs, Ks, Vs, cA, cB, ext, Qlen, Vlen);
    proj_gemm_kernel<<<dim3(64, 8, 3), 256, 0, stream>>>(
        cA, cB, ext, WQt, WKt, WVt, qa, ka, va, 0, Qlen, Vlen);
  } else {
    conv_kernel<<<2048, 256, 0, stream>>>(Qs, cA);
    conv_kernel<<<2048, 256, 0, stream>>>(Ks, cB);
    proj_gemm_kernel<<<dim3(64, 8, 2), 256, 0, stream>>>(
        cA, cB, cB, WQt, WKt, WVt, qa, ka, va, 0, Qlen, Vlen);
    conv_kernel<<<2048, 256, 0, stream>>>(Vs, cA);
    proj_gemm_kernel<<<dim3(64, 8, 1), 256, 0, stream>>>(
        cA, cA, cA, WQt, WKt, WVt, qa, ka, va, 2, Qlen, Vlen);
  }
  attn_kernel<<<dim3(128, 64), 256, 0, stream>>>(qa, ka, va, Qlen, Vlen, out);
}